// Round 11
// baseline (165.962 us; speedup 1.0000x reference)
//
#include <hip/hip_runtime.h>
#include <math.h>

// knnLoss: B=4, N=8192, k=3. Brute-force 3-NN, ONE kernel.
// R11 = R8's proven partial (43us, VGPR 60) + R7-style fused ticket tail
// (R8 ledger: separate merge kernel + launch cost 16.7us residual vs R4/R7's
// ~3-6us fused residuals; merge's real work is ~2us).
//   - 512 blocks x 512 threads, block=(Q,G,b); wave w stages its own
//     256-target subtile (32 octets, OCT4=7 padded) -> no main-body barriers.
//   - S=4 sources/lane; octet-min selection (5-bit packed idx); per-wave
//     exact 3-octet fixup; in-block 8-wave LDS merge -> triple per source.
//   - Tail: publish triple (atomicExch x3) -> threadfence -> group ticket on
//     (b,G); LAST of the 4 Q-blocks reads the other 3 triples (atomicAdd-0,
//     R7-proven coherence), merges, sqrt-sums, wave-reduce, per-batch atomics,
//     done-ticket finale writes out[0]. Grid caps occupancy at 4 waves/SIMD,
//     so tail VGPR pressure is free up to 128.
#define BATCH 4
#define NPTS 8192
#define NSRC 32768            // BATCH * NPTS
#define WAVES 8
#define NQ 4                  // target quarters (2048 targets each)
#define NG 32                 // source groups of 256 per batch
#define SPB 256               // sources per block (64 lanes x 4)
#define NOCTW 32              // octets per wave subtile (256 targets)
#define OCT4 7                // float4 per octet (6 data + 1 pad) = 112 B
#define SLOT4 (NOCTW * OCT4)  // 224 float4 per wave slot
#define NGROUPS (BATCH * NG)  // 128

typedef __attribute__((ext_vector_type(2))) float f2;

__device__ __forceinline__ float min3f(float a, float b, float c) {
    float d;
    asm("v_min3_f32 %0, %1, %2, %3" : "=v"(d) : "v"(a), "v"(b), "v"(c));
    return d;
}

// Branchless insert into sorted ascending triple; 4 ops via med3.
__device__ __forceinline__ void insert3(float d, float& a0, float& a1, float& a2) {
    float h = fmaxf(a1, d);
    float m = __builtin_amdgcn_fmed3f(a0, a1, d);
    a2 = fminf(a2, h);
    a1 = m;
    a0 = fminf(a0, d);
}

// Merge two sorted-ascending triples -> the sorted 3 smallest of the union.
__device__ __forceinline__ void merge33(float a0, float a1, float a2,
                                        float& b0, float& b1, float& b2) {
    float s0 = fminf(a0, b0);
    float h  = fmaxf(a0, b0);
    float m  = fminf(a1, b1);
    float mm = fminf(a2, b2);
    b1 = fminf(h, m);
    b2 = __builtin_amdgcn_fmed3f(h, m, mm);
    b0 = s0;
}

// Exact recompute of one octet (6 float4s, w rebuilt) -> insert into chain.
__device__ __forceinline__ void octet_fix(const float4* ob, f2 nx, f2 ny, f2 nz,
                                          float& c0, float& c1, float& c2) {
    float4 X0 = ob[0], X1 = ob[1], Y0 = ob[2], Y1 = ob[3], Z0 = ob[4], Z1 = ob[5];
    f2 xs0 = (f2){X0.x, X0.y}, xs1 = (f2){X0.z, X0.w};
    f2 xs2 = (f2){X1.x, X1.y}, xs3 = (f2){X1.z, X1.w};
    f2 ys0 = (f2){Y0.x, Y0.y}, ys1 = (f2){Y0.z, Y0.w};
    f2 ys2 = (f2){Y1.x, Y1.y}, ys3 = (f2){Y1.z, Y1.w};
    f2 zs0 = (f2){Z0.x, Z0.y}, zs1 = (f2){Z0.z, Z0.w};
    f2 zs2 = (f2){Z1.x, Z1.y}, zs3 = (f2){Z1.z, Z1.w};
    f2 w0 = zs0 * zs0; w0 = __builtin_elementwise_fma(ys0, ys0, w0);
    w0 = __builtin_elementwise_fma(xs0, xs0, w0);
    f2 w1 = zs1 * zs1; w1 = __builtin_elementwise_fma(ys1, ys1, w1);
    w1 = __builtin_elementwise_fma(xs1, xs1, w1);
    f2 w2 = zs2 * zs2; w2 = __builtin_elementwise_fma(ys2, ys2, w2);
    w2 = __builtin_elementwise_fma(xs2, xs2, w2);
    f2 w3 = zs3 * zs3; w3 = __builtin_elementwise_fma(ys3, ys3, w3);
    w3 = __builtin_elementwise_fma(xs3, xs3, w3);
    f2 pa = __builtin_elementwise_fma(zs0, nz, w0);
    pa = __builtin_elementwise_fma(ys0, ny, pa);
    pa = __builtin_elementwise_fma(xs0, nx, pa);
    f2 pb = __builtin_elementwise_fma(zs1, nz, w1);
    pb = __builtin_elementwise_fma(ys1, ny, pb);
    pb = __builtin_elementwise_fma(xs1, nx, pb);
    f2 pc = __builtin_elementwise_fma(zs2, nz, w2);
    pc = __builtin_elementwise_fma(ys2, ny, pc);
    pc = __builtin_elementwise_fma(xs2, nx, pc);
    f2 pd = __builtin_elementwise_fma(zs3, nz, w3);
    pd = __builtin_elementwise_fma(ys3, ny, pd);
    pd = __builtin_elementwise_fma(xs3, nx, pd);
    insert3(pa.x, c0, c1, c2);
    insert3(pa.y, c0, c1, c2);
    insert3(pb.x, c0, c1, c2);
    insert3(pb.y, c0, c1, c2);
    insert3(pc.x, c0, c1, c2);
    insert3(pc.y, c0, c1, c2);
    insert3(pd.x, c0, c1, c2);
    insert3(pd.y, c0, c1, c2);
}

__global__ __launch_bounds__(512) void knn_fused(const float* __restrict__ src,
                                                 const float* __restrict__ tgt,
                                                 float* __restrict__ acc,
                                                 float* __restrict__ cnt,
                                                 unsigned* __restrict__ done,
                                                 unsigned* __restrict__ groupT,
                                                 float* __restrict__ part,
                                                 float* __restrict__ out) {
    __shared__ float tsf[WAVES * SLOT4 * 4];  // 7168 floats = 28672 B
    const int tid = threadIdx.x;
    const int lane = tid & 63, wave = tid >> 6;
    const int Q = blockIdx.x, G = blockIdx.y, b = blockIdx.z;

    // ---- Stage (R8-proven): lane l loads targets 4l..4l+3 of this wave's
    // 256-target subtile, writes half-octet h=l&1 of octet o=l>>1.
    {
        const float4* tf4 = (const float4*)(tgt +
            ((size_t)b * NPTS + Q * 2048 + wave * 256 + 4 * lane) * 3);
        float4 f0 = tf4[0], f1 = tf4[1], f2v = tf4[2];
        float tx[4], ty[4], tz[4];
        tx[0] = f0.x;  ty[0] = f0.y;  tz[0] = f0.z;
        tx[1] = f0.w;  ty[1] = f1.x;  tz[1] = f1.y;
        tx[2] = f1.z;  ty[2] = f1.w;  tz[2] = f2v.x;
        tx[3] = f2v.y; ty[3] = f2v.z; tz[3] = f2v.w;
        #pragma unroll
        for (int j = 0; j < 4; ++j) {
            if (!(tx[j] != 0.f || ty[j] != 0.f || tz[j] != 0.f)) {
                tx[j] = 1e12f; ty[j] = 1e12f; tz[j] = 1e12f;  // sentinel
            }
        }
        int o = lane >> 1, h = lane & 1;
        float4* slot = ((float4*)tsf) + wave * SLOT4 + o * OCT4;
        slot[0 + h] = make_float4(tx[0], tx[1], tx[2], tx[3]);  // X_h
        slot[2 + h] = make_float4(ty[0], ty[1], ty[2], ty[3]);  // Y_h
        slot[4 + h] = make_float4(tz[0], tz[1], tz[2], tz[3]);  // Z_h
    }
    // No barrier: each wave reads only the slot it wrote (lgkmcnt orders).

    // ---- Source precompute: lane owns 4 sources G*256 + s*64 + lane.
    f2 nx[4], ny[4], nz[4];
    #pragma unroll
    for (int s = 0; s < 4; ++s) {
        const float* sp = src + ((size_t)b * NPTS + G * 256 + s * 64 + lane) * 3;
        float ax = sp[0], ay = sp[1], az = sp[2];
        nx[s] = (f2){-2.f * ax, -2.f * ax};
        ny[s] = (f2){-2.f * ay, -2.f * ay};
        nz[s] = (f2){-2.f * az, -2.f * az};
    }

    // ---- Hot loop (R8-proven): 32 octets, 6 broadcast b128 reads, S=4.
    float q0[4], q1[4], q2c[4];
    #pragma unroll
    for (int s = 0; s < 4; ++s) { q0[s] = q1[s] = q2c[s] = 3e38f; }

    const float4* tsv = ((const float4*)tsf) + wave * SLOT4;
    #pragma unroll 2
    for (int o = 0; o < NOCTW; ++o) {
        float4 X0 = tsv[7 * o + 0], X1 = tsv[7 * o + 1];
        float4 Y0 = tsv[7 * o + 2], Y1 = tsv[7 * o + 3];
        float4 Z0 = tsv[7 * o + 4], Z1 = tsv[7 * o + 5];
        f2 xs0 = (f2){X0.x, X0.y}, xs1 = (f2){X0.z, X0.w};
        f2 xs2 = (f2){X1.x, X1.y}, xs3 = (f2){X1.z, X1.w};
        f2 ys0 = (f2){Y0.x, Y0.y}, ys1 = (f2){Y0.z, Y0.w};
        f2 ys2 = (f2){Y1.x, Y1.y}, ys3 = (f2){Y1.z, Y1.w};
        f2 zs0 = (f2){Z0.x, Z0.y}, zs1 = (f2){Z0.z, Z0.w};
        f2 zs2 = (f2){Z1.x, Z1.y}, zs3 = (f2){Z1.z, Z1.w};
        // w = |t|^2 once per octet, amortized over 4 sources.
        f2 w0 = zs0 * zs0; w0 = __builtin_elementwise_fma(ys0, ys0, w0);
        w0 = __builtin_elementwise_fma(xs0, xs0, w0);
        f2 w1 = zs1 * zs1; w1 = __builtin_elementwise_fma(ys1, ys1, w1);
        w1 = __builtin_elementwise_fma(xs1, xs1, w1);
        f2 w2 = zs2 * zs2; w2 = __builtin_elementwise_fma(ys2, ys2, w2);
        w2 = __builtin_elementwise_fma(xs2, xs2, w2);
        f2 w3 = zs3 * zs3; w3 = __builtin_elementwise_fma(ys3, ys3, w3);
        w3 = __builtin_elementwise_fma(xs3, xs3, w3);
        #pragma unroll
        for (int s = 0; s < 4; ++s) {
            f2 pa = __builtin_elementwise_fma(zs0, nz[s], w0);
            pa = __builtin_elementwise_fma(ys0, ny[s], pa);
            pa = __builtin_elementwise_fma(xs0, nx[s], pa);
            f2 pb = __builtin_elementwise_fma(zs1, nz[s], w1);
            pb = __builtin_elementwise_fma(ys1, ny[s], pb);
            pb = __builtin_elementwise_fma(xs1, nx[s], pb);
            f2 pc = __builtin_elementwise_fma(zs2, nz[s], w2);
            pc = __builtin_elementwise_fma(ys2, ny[s], pc);
            pc = __builtin_elementwise_fma(xs2, nx[s], pc);
            f2 pd = __builtin_elementwise_fma(zs3, nz[s], w3);
            pd = __builtin_elementwise_fma(ys3, ny[s], pd);
            pd = __builtin_elementwise_fma(xs3, nx[s], pd);
            float m1 = min3f(pa.x, pa.y, pb.x);
            float m2 = min3f(pb.y, pc.x, pc.y);
            float m3 = min3f(pd.x, pd.y, m1);
            float m4 = fminf(m2, m3);
            unsigned u = (__float_as_uint(m4) & 0xFFFFFFE0u) | (unsigned)o;
            insert3(__uint_as_float(u), q0[s], q1[s], q2c[s]);
        }
    }

    // ---- Exact fixup (<=3 candidate octets per source).
    float e0[4], e1[4], e2[4];
    #pragma unroll
    for (int s = 0; s < 4; ++s) {
        e0[s] = 3e38f; e1[s] = 3e38f; e2[s] = 3e38f;
        octet_fix(tsv + 7 * (int)(__float_as_uint(q0[s]) & 31u),
                  nx[s], ny[s], nz[s], e0[s], e1[s], e2[s]);
        octet_fix(tsv + 7 * (int)(__float_as_uint(q1[s]) & 31u),
                  nx[s], ny[s], nz[s], e0[s], e1[s], e2[s]);
        octet_fix(tsv + 7 * (int)(__float_as_uint(q2c[s]) & 31u),
                  nx[s], ny[s], nz[s], e0[s], e1[s], e2[s]);
    }

    // ---- In-block merge across 8 waves (reuse tsf; 6144 floats).
    __syncthreads();
    #pragma unroll
    for (int s = 0; s < 4; ++s) {
        int idx = ((s * 8 + wave) * 64 + lane) * 3;
        tsf[idx] = e0[s]; tsf[idx + 1] = e1[s]; tsf[idx + 2] = e2[s];
    }
    __syncthreads();

    const int gq = b * NG + G;  // group id 0..127
    float a0 = 3e38f, a1 = 3e38f, a2 = 3e38f;
    if (tid < SPB) {
        int s = tid >> 6, l = tid & 63;
        int base = (s * 8 * 64 + l) * 3;
        a0 = tsf[base]; a1 = tsf[base + 1]; a2 = tsf[base + 2];
        #pragma unroll
        for (int w = 1; w < 8; ++w) {
            int bse = ((s * 8 + w) * 64 + l) * 3;
            merge33(tsf[bse], tsf[bse + 1], tsf[bse + 2], a0, a1, a2);
        }
        // Publish this quarter's triple (device-scope, R7-proven pattern).
        size_t pidx = ((size_t)Q * NSRC + (size_t)b * NPTS + G * 256 + tid) * 3;
        atomicExch(&part[pidx + 0], a0);
        atomicExch(&part[pidx + 1], a1);
        atomicExch(&part[pidx + 2], a2);
    }
    __threadfence();
    __syncthreads();

    // ---- Group ticket: LAST of the 4 Q-blocks merges all quarters.
    unsigned* tflag = (unsigned*)(tsf + 7000);
    if (tid == 0) tflag[0] = atomicAdd(&groupT[gq], 1u);
    __syncthreads();
    if (tflag[0] != 3u) return;
    __threadfence();  // acquire before reading others' partials

    float sv = 0.f, cv = 0.f;
    if (tid < SPB) {
        size_t gsrc = (size_t)b * NPTS + G * 256 + tid;
        #pragma unroll
        for (int q = 0; q < NQ; ++q) {
            if (q == Q) continue;
            size_t qidx = ((size_t)q * NSRC + gsrc) * 3;
            float p0 = atomicAdd(&part[qidx + 0], 0.f);
            float p1 = atomicAdd(&part[qidx + 1], 0.f);
            float p2 = atomicAdd(&part[qidx + 2], 0.f);
            merge33(p0, p1, p2, a0, a1, a2);
        }
        const float* sp = src + gsrc * 3;
        float sx = sp[0], sy = sp[1], sz = sp[2];
        bool valid = (sx != 0.f) || (sy != 0.f) || (sz != 0.f);
        float qq = sx * sx + sy * sy + sz * sz;  // deferred |s|^2
        sv = valid ? (sqrtf(fmaxf(a0 + qq, 0.f)) + sqrtf(fmaxf(a1 + qq, 0.f)) +
                      sqrtf(fmaxf(a2 + qq, 0.f)))
                   : 0.f;
        cv = valid ? 1.f : 0.f;
    }
    for (int off = 32; off >= 1; off >>= 1) {
        sv += __shfl_down(sv, off);
        cv += __shfl_down(cv, off);
    }
    float* red = tsf + 7008;
    __syncthreads();  // tflag read done before reuse
    if (lane == 0) { red[wave] = sv; red[wave + 8] = cv; }
    __syncthreads();
    if (tid == 0) {
        float ss = 0.f, cc = 0.f;
        #pragma unroll
        for (int w = 0; w < 8; ++w) { ss += red[w]; cc += red[w + 8]; }
        atomicAdd(&acc[b], ss);
        atomicAdd(&cnt[b], cc);
        __threadfence();
        unsigned dt = atomicAdd(done, 1u);
        if (dt == (unsigned)(NGROUPS - 1)) {
            float loss = 0.f;
            #pragma unroll
            for (int bb = 0; bb < BATCH; ++bb) {
                float as = atomicAdd(&acc[bb], 0.f);
                float ac = atomicAdd(&cnt[bb], 0.f);
                loss += as / (ac * 3.0f);
            }
            out[0] = loss * (1.0f / BATCH);
        }
    }
}

extern "C" void kernel_launch(void* const* d_in, const int* in_sizes, int n_in,
                              void* d_out, int out_size, void* d_ws, size_t ws_size,
                              hipStream_t stream) {
    const float* src = (const float*)d_in[0];
    const float* tgt = (const float*)d_in[1];
    float* out = (float*)d_out;

    // ws: [0,16) acc[4]; [16,32) cnt[4]; [32,36) done; [64,576) groupT[128];
    //     [1024, 1024+1572864) partial triples (4 x 32768 x 3 x 4B).
    float* acc = (float*)d_ws;
    float* cnt = acc + 4;
    unsigned* done = (unsigned*)((char*)d_ws + 32);
    unsigned* groupT = (unsigned*)((char*)d_ws + 64);
    float* part = (float*)((char*)d_ws + 1024);

    hipMemsetAsync(d_ws, 0, 1024, stream);  // zero header (graph-capturable)

    dim3 g1(NQ, NG, BATCH);  // 4 x 32 x 4 = 512 blocks x 512 threads
    knn_fused<<<g1, 512, 0, stream>>>(src, tgt, acc, cnt, done, groupT,
                                      part, out);
}